// Round 10
// baseline (950.564 us; speedup 1.0000x reference)
//
#include <hip/hip_runtime.h>

#define NN 20000
#define NE 320000
#define DIMX 256
#define NHEADS 8
#define HC 32
#define EDIMX 32
#define DFFX 1024
#define TOT (NE + NN)
#define NGROUPS (TOT / 16)  // 21250, exact

using f32x4 = __attribute__((ext_vector_type(4))) float;
using bfrag = __attribute__((ext_vector_type(8))) short;  // 8 bf16 = 4 VGPRs

__device__ __forceinline__ float b2f(unsigned short u) {
  return __uint_as_float(((unsigned)u) << 16);
}
__device__ __forceinline__ unsigned short f2b(float f) {
  unsigned u = __float_as_uint(f);
  u += 0x7FFF + ((u >> 16) & 1);
  return (unsigned short)(u >> 16);
}

// ---------------- dtype detect: 1 = inputs are f32, 0 = inputs are bf16 ----------------
__global__ void k_detect(const unsigned short* __restrict__ in, int* __restrict__ flag) {
  __shared__ int cnt_s;
  if (threadIdx.x == 0) cnt_s = 0;
  __syncthreads();
  int c = 0;
  for (int i = threadIdx.x; i < 4096; i += 256) {
    int ex = (in[i] >> 7) & 0xFF;
    if (ex >= 0xC6) c++;
  }
  atomicAdd(&cnt_s, c);
  __syncthreads();
  if (threadIdx.x == 0) flag[0] = (cnt_s > 64) ? 1 : 0;
}

// ---------------- input -> f32 + bf16 shadow ----------------
__global__ void k_cvt_dual(const void* __restrict__ in, float* __restrict__ outf,
                           unsigned short* __restrict__ outb, int n,
                           const int* __restrict__ flag) {
  int i = blockIdx.x * 256 + threadIdx.x;
  if (i >= n) return;
  if (flag[0]) {
    float v = ((const float*)in)[i];
    outf[i] = v;
    outb[i] = f2b(v);
  } else {
    unsigned short u = ((const unsigned short*)in)[i];
    outf[i] = b2f(u);
    outb[i] = u;
  }
}

// ---------------- fused multi-segment param convert ----------------
struct CvtArgs {
  const void* src[20];
  float* dst[20];
  int n[20];
};
__global__ void k_cvt_multi(CvtArgs a, const int* __restrict__ flag) {
  int seg = blockIdx.y;
  int n = a.n[seg];
  int i = blockIdx.x * 256 + threadIdx.x;
  if (i >= n) return;
  if (flag[0]) a.dst[seg][i] = ((const float*)a.src[seg])[i];
  else a.dst[seg][i] = b2f(((const unsigned short*)a.src[seg])[i]);
}

// ---------------- f32 [K][N] -> bf16 [N][K] transpose ----------------
__global__ __launch_bounds__(256) void k_transpose(const float* __restrict__ in,
                                                   unsigned short* __restrict__ out,
                                                   int K, int N) {
  __shared__ float t[32][33];
  int n0 = blockIdx.x * 32, k0 = blockIdx.y * 32;
  int tx = threadIdx.x & 31, ty = threadIdx.x >> 5;  // 32 x 8
#pragma unroll
  for (int i = 0; i < 4; i++)
    t[ty + i * 8][tx] = in[(size_t)(k0 + ty + i * 8) * N + n0 + tx];
  __syncthreads();
#pragma unroll
  for (int i = 0; i < 4; i++)
    out[(size_t)(n0 + ty + i * 8) * K + k0 + tx] = f2b(t[tx][ty + i * 8]);
}

// ---------------- edge count (int atomics only) ----------------
__global__ void k_edge_count(const int* __restrict__ dst, int* __restrict__ cnt, int E) {
  int e = blockIdx.x * 256 + threadIdx.x;
  if (e >= E) return;
  atomicAdd(&cnt[dst[e]], 1);
}

// ---------------- single-block scan -> rowptr ----------------
__global__ void k_scan(const int* __restrict__ cnt, int* __restrict__ rowptr, int N) {
  __shared__ int sums[256];
  int t = threadIdx.x;
  int chunk = (N + 255) / 256;
  int lo = t * chunk, hi = lo + chunk;
  if (hi > N) hi = N;
  if (lo > N) lo = N;
  int s = 0;
  for (int n = lo; n < hi; n++) s += cnt[n] + 1;
  sums[t] = s;
  __syncthreads();
  for (int off = 1; off < 256; off <<= 1) {
    int v = (t >= off) ? sums[t - off] : 0;
    __syncthreads();
    sums[t] += v;
    __syncthreads();
  }
  int run = sums[t] - s;  // exclusive prefix
  for (int n = lo; n < hi; n++) { rowptr[n] = run; run += cnt[n] + 1; }
  if (t == 255) rowptr[N] = run;
}

// ---------------- CSR fill (edges + self loops), also records dst per slot ----------------
__global__ void k_fill(const int* __restrict__ dst, const int* __restrict__ rowptr,
                       int* __restrict__ fill, int* __restrict__ eidx,
                       int* __restrict__ dstp, int N, int E) {
  int t = blockIdx.x * 256 + threadIdx.x;
  if (t < E) {
    int d = dst[t];
    int pos = rowptr[d] + atomicAdd(&fill[d], 1);
    eidx[pos] = t;
    dstp[pos] = d;
  } else if (t < E + N) {
    int n = t - E;
    int pos = rowptr[n + 1] - 1;
    eidx[pos] = E + n;  // self loop id
    dstp[pos] = n;
  }
}

// ---------------- loop_ea from raw ew input (flag-dispatched dtype) ----------------
__global__ __launch_bounds__(256) void k_lea(const void* __restrict__ ew,
                                             const int* __restrict__ rowptr,
                                             const int* __restrict__ eidx,
                                             float* __restrict__ lea, int N,
                                             const int* __restrict__ flag) {
  int f = flag[0];
  int wave = threadIdx.x >> 6, lane = threadIdx.x & 63;
  int node = blockIdx.x * 4 + wave;
  if (node >= N) return;
  int begin = rowptr[node], end = rowptr[node + 1] - 1;  // exclude self-loop slot
  int ch = lane & 31, half = lane >> 5;
  float s = 0.f;
  for (int p = begin + half; p < end; p += 2) {
    int eid = eidx[p];
    size_t idx = (size_t)eid * EDIMX + ch;
    s += f ? ((const float*)ew)[idx] : b2f(((const unsigned short*)ew)[idx]);
  }
  s += __shfl_xor(s, 32, 64);
  int deg = end - begin;
  if (lane < 32) lea[(size_t)node * EDIMX + ch] = s / (float)(deg > 0 ? deg : 1);
}

// ---------------- build CSR-ordered src ids + edge attrs (bf16) from raw ew ----------------
__global__ __launch_bounds__(256) void k_build_perm(const int* __restrict__ eidx,
                                                    const int* __restrict__ src,
                                                    const void* __restrict__ ew,
                                                    const float* __restrict__ lea,
                                                    int* __restrict__ srcp,
                                                    unsigned short* __restrict__ eab,
                                                    int total, int E,
                                                    const int* __restrict__ flag) {
  int f = flag[0];
  int g = blockIdx.x * 8 + (threadIdx.x >> 5);
  int lane = threadIdx.x & 31;
  if (g >= total) return;
  int eid = eidx[g];
  unsigned short v;
  int s;
  if (eid < E) {
    s = src[eid];
    size_t idx = (size_t)eid * EDIMX + lane;
    v = f ? f2b(((const float*)ew)[idx]) : ((const unsigned short*)ew)[idx];
  } else {
    s = eid - E;
    v = f2b(lea[(size_t)(eid - E) * EDIMX + lane]);
  }
  if (lane == 0) srcp[g] = s;
  eab[(size_t)g * EDIMX + lane] = v;
}

// ---------------- MFMA bf16 GEMM with NT n-tiles per block (A reused via L1) ----------------
// C[M,N] = A[M,K] @ BT[N,K]^T; block covers 64 rows x NT*64 cols.
template <bool BIAS, bool RELU, bool OUTBF16, int NT>
__global__ __launch_bounds__(256) void k_gemm_mfma(const unsigned short* __restrict__ A,
                                                   const unsigned short* __restrict__ BT,
                                                   const float* __restrict__ bias,
                                                   void* __restrict__ C, int M, int K, int N) {
  int tid = threadIdx.x;
  int wave = tid >> 6, lane = tid & 63;
  int quad = lane >> 4, l16 = lane & 15;
  int m0 = blockIdx.x * 64 + (wave & 1) * 32;
  int mA0 = m0 + l16;
  if (mA0 > M - 1) mA0 = M - 1;
  int mA1 = m0 + 16 + l16;
  if (mA1 > M - 1) mA1 = M - 1;
  const bfrag* a0p = (const bfrag*)(A + (size_t)mA0 * K + quad * 8);
  const bfrag* a1p = (const bfrag*)(A + (size_t)mA1 * K + quad * 8);
  int ksteps = K >> 5;
#pragma unroll
  for (int j = 0; j < NT; j++) {
    int n0 = (blockIdx.y * NT + j) * 64 + (wave >> 1) * 32;
    const bfrag* b0p = (const bfrag*)(BT + (size_t)(n0 + l16) * K + quad * 8);
    const bfrag* b1p = (const bfrag*)(BT + (size_t)(n0 + 16 + l16) * K + quad * 8);
    f32x4 acc00 = {0.f, 0.f, 0.f, 0.f}, acc01 = {0.f, 0.f, 0.f, 0.f};
    f32x4 acc10 = {0.f, 0.f, 0.f, 0.f}, acc11 = {0.f, 0.f, 0.f, 0.f};
    for (int kk = 0; kk < ksteps; kk++) {
      bfrag a0 = a0p[kk * 4];
      bfrag a1 = a1p[kk * 4];
      bfrag b0 = b0p[kk * 4];
      bfrag b1 = b1p[kk * 4];
      acc00 = __builtin_amdgcn_mfma_f32_16x16x32_bf16(a0, b0, acc00, 0, 0, 0);
      acc01 = __builtin_amdgcn_mfma_f32_16x16x32_bf16(a0, b1, acc01, 0, 0, 0);
      acc10 = __builtin_amdgcn_mfma_f32_16x16x32_bf16(a1, b0, acc10, 0, 0, 0);
      acc11 = __builtin_amdgcn_mfma_f32_16x16x32_bf16(a1, b1, acc11, 0, 0, 0);
    }
    float bv0 = 0.f, bv1 = 0.f;
    if (BIAS) {
      bv0 = bias[n0 + l16];
      bv1 = bias[n0 + 16 + l16];
    }
    int col0 = n0 + l16, col1 = n0 + 16 + l16;
#pragma unroll
    for (int r = 0; r < 4; r++) {
      int row0 = m0 + quad * 4 + r;
      int row1 = m0 + 16 + quad * 4 + r;
      float v00 = acc00[r] + bv0, v01 = acc01[r] + bv1;
      float v10 = acc10[r] + bv0, v11 = acc11[r] + bv1;
      if (RELU) {
        v00 = fmaxf(v00, 0.f); v01 = fmaxf(v01, 0.f);
        v10 = fmaxf(v10, 0.f); v11 = fmaxf(v11, 0.f);
      }
      if (row0 < M) {
        if (OUTBF16) {
          ((unsigned short*)C)[(size_t)row0 * N + col0] = f2b(v00);
          ((unsigned short*)C)[(size_t)row0 * N + col1] = f2b(v01);
        } else {
          ((float*)C)[(size_t)row0 * N + col0] = v00;
          ((float*)C)[(size_t)row0 * N + col1] = v01;
        }
      }
      if (row1 < M) {
        if (OUTBF16) {
          ((unsigned short*)C)[(size_t)row1 * N + col0] = f2b(v10);
          ((unsigned short*)C)[(size_t)row1 * N + col1] = f2b(v11);
        } else {
          ((float*)C)[(size_t)row1 * N + col0] = v10;
          ((float*)C)[(size_t)row1 * N + col1] = v11;
        }
      }
    }
  }
}

// ---------------- MFMA-based edge score: 1 wave = 16 CSR slots ----------------
// xlr rows are [xl(256) | xr(256)] per node, stride 512.
__global__ __launch_bounds__(256) void k_score_mfma(
    const unsigned short* __restrict__ xlr, const unsigned short* __restrict__ eab,
    const int* __restrict__ srcp, const int* __restrict__ dstp,
    const unsigned short* __restrict__ WET, const float* __restrict__ att,
    float* __restrict__ score, int ngroups) {
  __shared__ unsigned short We_s[256 * 40];      // WET rows padded 32->40 (20.5 KB)
  __shared__ unsigned short ee_s[4][16 * 260];   // per-wave EE staging (33.3 KB)
  {
    int tid = threadIdx.x;  // one row per thread: 32 ushorts = 8x ushort4
#pragma unroll
    for (int j = 0; j < 8; j++)
      *(ushort4*)&We_s[tid * 40 + j * 4] = *(const ushort4*)(WET + tid * 32 + j * 4);
  }
  __syncthreads();
  int wave = threadIdx.x >> 6, lane = threadIdx.x & 63;
  int quad = lane >> 4, l16 = lane & 15;
  int g = blockIdx.x * 4 + wave;
  if (g >= ngroups) return;
  int pbase = g * 16;
  const bfrag ea = *(const bfrag*)(eab + ((size_t)(pbase + l16) << 5) + quad * 8);
  f32x4 zero4 = {0.f, 0.f, 0.f, 0.f};
  f32x4 acc[16];
#pragma unroll
  for (int t = 0; t < 16; t++) {
    bfrag bw = *(const bfrag*)&We_s[(t * 16 + l16) * 40 + quad * 8];
    acc[t] = __builtin_amdgcn_mfma_f32_16x16x32_bf16(ea, bw, zero4, 0, 0, 0);
  }
#pragma unroll
  for (int t = 0; t < 16; t++) {
#pragma unroll
    for (int r = 0; r < 4; r++)
      ee_s[wave][(quad * 4 + r) * 260 + t * 16 + l16] = f2b(acc[t][r]);
  }
  int c0 = lane * 4;
  float4 a4 = *(const float4*)(att + c0);
  for (int e = 0; e < 16; e += 2) {
    int p0 = pbase + e, p1 = pbase + e + 1;
    int s0 = srcp[p0], d0 = dstp[p0];
    int s1 = srcp[p1], d1 = dstp[p1];
    ushort4 vl0 = *(const ushort4*)(xlr + ((size_t)s0 << 9) + c0);
    ushort4 vr0 = *(const ushort4*)(xlr + ((size_t)d0 << 9) + 256 + c0);
    ushort4 vl1 = *(const ushort4*)(xlr + ((size_t)s1 << 9) + c0);
    ushort4 vr1 = *(const ushort4*)(xlr + ((size_t)d1 << 9) + 256 + c0);
    ushort4 eu0 = *(const ushort4*)&ee_s[wave][e * 260 + c0];
    ushort4 eu1 = *(const ushort4*)&ee_s[wave][(e + 1) * 260 + c0];
    float z00 = b2f(vl0.x) + b2f(vr0.x) + b2f(eu0.x);
    float z01 = b2f(vl0.y) + b2f(vr0.y) + b2f(eu0.y);
    float z02 = b2f(vl0.z) + b2f(vr0.z) + b2f(eu0.z);
    float z03 = b2f(vl0.w) + b2f(vr0.w) + b2f(eu0.w);
    float z10 = b2f(vl1.x) + b2f(vr1.x) + b2f(eu1.x);
    float z11 = b2f(vl1.y) + b2f(vr1.y) + b2f(eu1.y);
    float z12 = b2f(vl1.z) + b2f(vr1.z) + b2f(eu1.z);
    float z13 = b2f(vl1.w) + b2f(vr1.w) + b2f(eu1.w);
    z00 = z00 > 0.f ? z00 : 0.2f * z00; z01 = z01 > 0.f ? z01 : 0.2f * z01;
    z02 = z02 > 0.f ? z02 : 0.2f * z02; z03 = z03 > 0.f ? z03 : 0.2f * z03;
    z10 = z10 > 0.f ? z10 : 0.2f * z10; z11 = z11 > 0.f ? z11 : 0.2f * z11;
    z12 = z12 > 0.f ? z12 : 0.2f * z12; z13 = z13 > 0.f ? z13 : 0.2f * z13;
    float sc0 = z00 * a4.x + z01 * a4.y + z02 * a4.z + z03 * a4.w;
    float sc1 = z10 * a4.x + z11 * a4.y + z12 * a4.z + z13 * a4.w;
    sc0 += __shfl_xor(sc0, 1, 64);
    sc1 += __shfl_xor(sc1, 1, 64);
    sc0 += __shfl_xor(sc0, 2, 64);
    sc1 += __shfl_xor(sc1, 2, 64);
    sc0 += __shfl_xor(sc0, 4, 64);
    sc1 += __shfl_xor(sc1, 4, 64);
    if ((lane & 7) == 0) {
      int h = lane >> 3;
      score[(size_t)p0 * 8 + h] = sc0;
      score[(size_t)p1 * 8 + h] = sc1;
    }
  }
}

// ---------------- node-parallel softmax + aggregate (4-edge unrolled gathers) ----------------
__global__ __launch_bounds__(256) void k_agg(const unsigned short* __restrict__ xlr,
                                             const float* __restrict__ score,
                                             const int* __restrict__ srcp,
                                             const float* __restrict__ bias,
                                             const int* __restrict__ rowptr,
                                             float* __restrict__ out, int N) {
  int wave = threadIdx.x >> 6, lane = threadIdx.x & 63;
  int node = blockIdx.x * 4 + wave;
  if (node >= N) return;
  int begin = rowptr[node], end = rowptr[node + 1];
  int head = lane >> 3, sl = lane & 7;
  float m = -3.4e38f;
  for (int p = begin + sl; p < end; p += 8)
    m = fmaxf(m, score[(size_t)p * 8 + head]);
  m = fmaxf(m, __shfl_xor(m, 1, 64));
  m = fmaxf(m, __shfl_xor(m, 2, 64));
  m = fmaxf(m, __shfl_xor(m, 4, 64));
  float ssum = 0.f;
  for (int p = begin + sl; p < end; p += 8)
    ssum += __expf(score[(size_t)p * 8 + head] - m);
  ssum += __shfl_xor(ssum, 1, 64);
  ssum += __shfl_xor(ssum, 2, 64);
  ssum += __shfl_xor(ssum, 4, 64);
  float linv = 1.f / ssum;
  int c0 = lane * 4;
  float ax = 0.f, ay = 0.f, az = 0.f, aw = 0.f;
  for (int p = begin; p < end; p += 4) {
    int e1 = end - 1;
    int q1 = (p + 1 < end) ? p + 1 : e1;
    int q2 = (p + 2 < end) ? p + 2 : e1;
    int q3 = (p + 3 < end) ? p + 3 : e1;
    int s0 = srcp[p], s1 = srcp[q1], s2 = srcp[q2], s3 = srcp[q3];
    float sc0 = score[(size_t)p * 8 + head];
    float sc1 = score[(size_t)q1 * 8 + head];
    float sc2 = score[(size_t)q2 * 8 + head];
    float sc3 = score[(size_t)q3 * 8 + head];
    ushort4 v0 = *(const ushort4*)(xlr + ((size_t)s0 << 9) + c0);
    ushort4 v1 = *(const ushort4*)(xlr + ((size_t)s1 << 9) + c0);
    ushort4 v2 = *(const ushort4*)(xlr + ((size_t)s2 << 9) + c0);
    ushort4 v3 = *(const ushort4*)(xlr + ((size_t)s3 << 9) + c0);
    float w0 = __expf(sc0 - m) * linv;
    float w1 = (p + 1 < end) ? __expf(sc1 - m) * linv : 0.f;
    float w2 = (p + 2 < end) ? __expf(sc2 - m) * linv : 0.f;
    float w3 = (p + 3 < end) ? __expf(sc3 - m) * linv : 0.f;
    ax += w0 * b2f(v0.x) + w1 * b2f(v1.x) + w2 * b2f(v2.x) + w3 * b2f(v3.x);
    ay += w0 * b2f(v0.y) + w1 * b2f(v1.y) + w2 * b2f(v2.y) + w3 * b2f(v3.y);
    az += w0 * b2f(v0.z) + w1 * b2f(v1.z) + w2 * b2f(v2.z) + w3 * b2f(v3.z);
    aw += w0 * b2f(v0.w) + w1 * b2f(v1.w) + w2 * b2f(v2.w) + w3 * b2f(v3.w);
  }
  float4 bia = *(const float4*)(bias + c0);
  float4 acc = make_float4(ax + bia.x, ay + bia.y, az + bia.z, aw + bia.w);
  ((float4*)out)[(size_t)node * 64 + lane] = acc;
}

// ---------------- BN stats (sum, sumsq per channel) ----------------
__global__ __launch_bounds__(256) void k_bnstats(const float* __restrict__ x,
                                                 float* __restrict__ sums, int N) {
  int c = threadIdx.x;
  float s = 0.f, sq = 0.f;
  for (int n = blockIdx.x; n < N; n += gridDim.x) {
    float v = x[(size_t)n * DIMX + c];
    s += v; sq += v * v;
  }
  atomicAdd(&sums[c], s);
  atomicAdd(&sums[DIMX + c], sq);
}

// ---------------- BN + leaky_relu(0.01) + residual (+ bf16 shadow) ----------------
template <bool FINAL>
__global__ __launch_bounds__(256) void k_bnapply(const float* __restrict__ x,
                                                 const float* __restrict__ res,
                                                 const float* __restrict__ sums,
                                                 const float* __restrict__ g,
                                                 const float* __restrict__ b,
                                                 void* __restrict__ out,
                                                 unsigned short* __restrict__ outb, int N,
                                                 const int* __restrict__ flag) {
  int i = blockIdx.x * 256 + threadIdx.x;
  if (i >= N * DIMX) return;
  int c = i & (DIMX - 1);
  float invn = 1.f / (float)N;
  float mu = sums[c] * invn;
  float var = sums[DIMX + c] * invn - mu * mu;
  float rstd = rsqrtf(var + 1e-5f);
  float y = (x[i] - mu) * rstd * g[c] + b[c];
  y = y > 0.f ? y : 0.01f * y;
  y += res[i];
  if (FINAL) {
    if (flag[0]) ((float*)out)[i] = y;
    else ((unsigned short*)out)[i] = f2b(y);
  } else {
    ((float*)out)[i] = y;
    outb[i] = f2b(y);
  }
}

extern "C" void kernel_launch(void* const* d_in, const int* in_sizes, int n_in,
                              void* d_out, int out_size, void* d_ws, size_t ws_size,
                              hipStream_t stream) {
  (void)in_sizes; (void)n_in; (void)out_size; (void)ws_size;
  const int* ei = (const int*)d_in[1];
  const int* srcp = ei;
  const int* dstp = ei + NE;

  char* w = (char*)d_ws;
  auto alloc = [&](size_t bytes) {
    char* p = w;
    w += (bytes + 255) & ~(size_t)255;
    return p;
  };
  float* H0 = (float*)alloc((size_t)NN * DIMX * 4);
  float* H1 = (float*)alloc((size_t)NN * DIMX * 4);
  float* G = (float*)alloc((size_t)NN * DIMX * 4);
  float* LEA = (float*)alloc((size_t)NN * EDIMX * 4);
  float* EWF = (float*)alloc((size_t)NE * EDIMX * 4);  // only used as FF1b alias now
  float* PAR = (float*)alloc((size_t)806656 * 4);
  float* SCORE = (float*)alloc((size_t)TOT * NHEADS * 4);  // 10.9 MB
  int* CNT = (int*)alloc((size_t)NN * 4);
  int* ROWPTR = (int*)alloc((size_t)(NN + 1) * 4);
  int* FILL = (int*)alloc((size_t)NN * 4);
  int* EIDX = (int*)alloc((size_t)TOT * 4);
  int* SRCP = (int*)alloc((size_t)TOT * 4);
  int* DSTP = (int*)alloc((size_t)TOT * 4);
  float* BNS = (float*)alloc(2 * DIMX * 4);
  int* FLAG = (int*)alloc(256);
  unsigned short* H0b = (unsigned short*)alloc((size_t)NN * DIMX * 2);
  unsigned short* H1b = (unsigned short*)alloc((size_t)NN * DIMX * 2);
  unsigned short* XLRb = (unsigned short*)alloc((size_t)NN * 512 * 2);  // [xl|xr] per node
  unsigned short* EAB = (unsigned short*)alloc((size_t)TOT * EDIMX * 2);
  unsigned short* WLRT0 = (unsigned short*)alloc((size_t)512 * DIMX * 2);  // [Wl^T;Wr^T]
  unsigned short* WLRT1 = (unsigned short*)alloc((size_t)512 * DIMX * 2);
  unsigned short* WET0 = (unsigned short*)alloc((size_t)DIMX * EDIMX * 2);  // We^T [256][32]
  unsigned short* WET1 = (unsigned short*)alloc((size_t)DIMX * EDIMX * 2);
  unsigned short* W1T = (unsigned short*)alloc((size_t)DIMX * DFFX * 2);
  unsigned short* W2T = (unsigned short*)alloc((size_t)DFFX * DIMX * 2);
  unsigned short* FF1b = (unsigned short*)EWF;  // 41 MB alias, FF phase only

  // ---- dtype detect + convert params to f32 / activations to f32+bf16 ----
  k_detect<<<1, 256, 0, stream>>>((const unsigned short*)d_in[0], FLAG);
  k_cvt_dual<<<(NN * DIMX + 255) / 256, 256, 0, stream>>>(d_in[0], H0, H0b, NN * DIMX, FLAG);
  static const int psz[20] = {65536, 65536, 8192, 256, 256,
                              65536, 65536, 8192, 256, 256,
                              256, 256, 256, 256, 256, 256,
                              262144, 1024, 262144, 256};
  float* pp[20];
  {
    CvtArgs ca;
    int off = 0;
    for (int i = 0; i < 20; i++) {
      pp[i] = PAR + off;
      off += psz[i];
      ca.src[i] = d_in[3 + i];
      ca.dst[i] = pp[i];
      ca.n[i] = psz[i];
    }
    k_cvt_multi<<<dim3(262144 / 256, 20), 256, 0, stream>>>(ca, FLAG);
  }
  const float* g_att[2] = {pp[3], pp[8]};
  const float* g_b[2] = {pp[4], pp[9]};
  const float* bn_g[3] = {pp[10], pp[12], pp[14]};
  const float* bn_b[3] = {pp[11], pp[13], pp[15]};
  const float* ff_b1 = pp[17];
  const float* ff_b2 = pp[19];

  // ---- weights: bf16 [N][K] transposes; Wl/Wr stacked into one [512][256] ----
  k_transpose<<<dim3(8, 8), 256, 0, stream>>>(pp[0], WLRT0, DIMX, DIMX);
  k_transpose<<<dim3(8, 8), 256, 0, stream>>>(pp[1], WLRT0 + 256 * DIMX, DIMX, DIMX);
  k_transpose<<<dim3(8, 8), 256, 0, stream>>>(pp[5], WLRT1, DIMX, DIMX);
  k_transpose<<<dim3(8, 8), 256, 0, stream>>>(pp[6], WLRT1 + 256 * DIMX, DIMX, DIMX);
  k_transpose<<<dim3(8, 1), 256, 0, stream>>>(pp[2], WET0, EDIMX, DIMX);
  k_transpose<<<dim3(8, 1), 256, 0, stream>>>(pp[7], WET1, EDIMX, DIMX);
  k_transpose<<<dim3(32, 8), 256, 0, stream>>>(pp[16], W1T, DIMX, DFFX);
  k_transpose<<<dim3(8, 32), 256, 0, stream>>>(pp[18], W2T, DFFX, DIMX);
  const unsigned short* WLRT[2] = {WLRT0, WLRT1};
  const unsigned short* WET[2] = {WET0, WET1};

  // ---- graph structure (shared by both GAT layers) ----
  hipMemsetAsync(CNT, 0, (size_t)NN * 4, stream);
  hipMemsetAsync(FILL, 0, (size_t)NN * 4, stream);
  k_edge_count<<<(NE + 255) / 256, 256, 0, stream>>>(dstp, CNT, NE);
  k_scan<<<1, 256, 0, stream>>>(CNT, ROWPTR, NN);
  k_fill<<<(TOT + 255) / 256, 256, 0, stream>>>(dstp, ROWPTR, FILL, EIDX, DSTP, NN, NE);
  k_lea<<<(NN + 3) / 4, 256, 0, stream>>>(d_in[2], ROWPTR, EIDX, LEA, NN, FLAG);
  k_build_perm<<<(TOT + 7) / 8, 256, 0, stream>>>(EIDX, srcp, d_in[2], LEA, SRCP, EAB, TOT, NE,
                                                  FLAG);

  const int MB = (NN + 63) / 64;  // 313
  auto run_gat = [&](const float* x, const unsigned short* xb, int li, int bi, float* hout,
                     unsigned short* houtb) {
    // XL|XR in one GEMM: N=512, NT=4 -> grid y=2
    k_gemm_mfma<false, false, true, 4><<<dim3(MB, 2), 256, 0, stream>>>(xb, WLRT[li], nullptr,
                                                                        XLRb, NN, DIMX, 512);
    k_score_mfma<<<(NGROUPS + 3) / 4, 256, 0, stream>>>(XLRb, EAB, SRCP, DSTP, WET[li],
                                                        g_att[li], SCORE, NGROUPS);
    k_agg<<<(NN + 3) / 4, 256, 0, stream>>>(XLRb, SCORE, SRCP, g_b[li], ROWPTR, G, NN);
    hipMemsetAsync(BNS, 0, 2 * DIMX * 4, stream);
    k_bnstats<<<128, 256, 0, stream>>>(G, BNS, NN);
    k_bnapply<false><<<(NN * DIMX + 255) / 256, 256, 0, stream>>>(G, x, BNS, bn_g[bi], bn_b[bi],
                                                                  hout, houtb, NN, FLAG);
  };

  run_gat(H0, H0b, 0, 0, H1, H1b);  // h1 = nf + lrelu(bn(gat1(nf)))
  run_gat(H1, H1b, 1, 1, H0, H0b);  // h2 = h1 + lrelu(bn(gat2(h1)))

  // ---- feed-forward (ff1 emits bf16 directly for ff2; FF1b aliases EWF) ----
  k_gemm_mfma<true, true, true, 4><<<dim3(MB, DFFX / 256), 256, 0, stream>>>(H0b, W1T, ff_b1,
                                                                             FF1b, NN, DIMX,
                                                                             DFFX);
  k_gemm_mfma<true, false, false, 4><<<dim3(MB, 1), 256, 0, stream>>>(FF1b, W2T, ff_b2, G, NN,
                                                                      DFFX, DIMX);
  hipMemsetAsync(BNS, 0, 2 * DIMX * 4, stream);
  k_bnstats<<<128, 256, 0, stream>>>(G, BNS, NN);
  k_bnapply<true><<<(NN * DIMX + 255) / 256, 256, 0, stream>>>(G, H0, BNS, bn_g[2], bn_b[2],
                                                               d_out, nullptr, NN, FLAG);
}

// Round 11
// 865.671 us; speedup vs baseline: 1.0981x; 1.0981x over previous
//
#include <hip/hip_runtime.h>

#define NN 20000
#define NE 320000
#define DIMX 256
#define NHEADS 8
#define HC 32
#define EDIMX 32
#define DFFX 1024
#define TOT (NE + NN)
#define NGROUPS (TOT / 16)  // 21250, exact

using f32x4 = __attribute__((ext_vector_type(4))) float;
using bfrag = __attribute__((ext_vector_type(8))) short;  // 8 bf16 = 4 VGPRs

__device__ __forceinline__ float b2f(unsigned short u) {
  return __uint_as_float(((unsigned)u) << 16);
}
__device__ __forceinline__ unsigned short f2b(float f) {
  unsigned u = __float_as_uint(f);
  u += 0x7FFF + ((u >> 16) & 1);
  return (unsigned short)(u >> 16);
}

// ---------------- dtype detect: 1 = inputs are f32, 0 = inputs are bf16 ----------------
__global__ void k_detect(const unsigned short* __restrict__ in, int* __restrict__ flag) {
  __shared__ int cnt_s;
  if (threadIdx.x == 0) cnt_s = 0;
  __syncthreads();
  int c = 0;
  for (int i = threadIdx.x; i < 4096; i += 256) {
    int ex = (in[i] >> 7) & 0xFF;
    if (ex >= 0xC6) c++;
  }
  atomicAdd(&cnt_s, c);
  __syncthreads();
  if (threadIdx.x == 0) flag[0] = (cnt_s > 64) ? 1 : 0;
}

// ---------------- input -> f32 + bf16 shadow ----------------
__global__ void k_cvt_dual(const void* __restrict__ in, float* __restrict__ outf,
                           unsigned short* __restrict__ outb, int n,
                           const int* __restrict__ flag) {
  int i = blockIdx.x * 256 + threadIdx.x;
  if (i >= n) return;
  if (flag[0]) {
    float v = ((const float*)in)[i];
    outf[i] = v;
    outb[i] = f2b(v);
  } else {
    unsigned short u = ((const unsigned short*)in)[i];
    outf[i] = b2f(u);
    outb[i] = u;
  }
}

// ---------------- fused multi-segment param convert ----------------
struct CvtArgs {
  const void* src[20];
  float* dst[20];
  int n[20];
};
__global__ void k_cvt_multi(CvtArgs a, const int* __restrict__ flag) {
  int seg = blockIdx.y;
  int n = a.n[seg];
  int i = blockIdx.x * 256 + threadIdx.x;
  if (i >= n) return;
  if (flag[0]) a.dst[seg][i] = ((const float*)a.src[seg])[i];
  else a.dst[seg][i] = b2f(((const unsigned short*)a.src[seg])[i]);
}

// ---------------- f32 [K][N] -> bf16 [N][K] transpose ----------------
__global__ __launch_bounds__(256) void k_transpose(const float* __restrict__ in,
                                                   unsigned short* __restrict__ out,
                                                   int K, int N) {
  __shared__ float t[32][33];
  int n0 = blockIdx.x * 32, k0 = blockIdx.y * 32;
  int tx = threadIdx.x & 31, ty = threadIdx.x >> 5;  // 32 x 8
#pragma unroll
  for (int i = 0; i < 4; i++)
    t[ty + i * 8][tx] = in[(size_t)(k0 + ty + i * 8) * N + n0 + tx];
  __syncthreads();
#pragma unroll
  for (int i = 0; i < 4; i++)
    out[(size_t)(n0 + ty + i * 8) * K + k0 + tx] = f2b(t[tx][ty + i * 8]);
}

// ---------------- edge count (int atomics only) ----------------
__global__ void k_edge_count(const int* __restrict__ dst, int* __restrict__ cnt, int E) {
  int e = blockIdx.x * 256 + threadIdx.x;
  if (e >= E) return;
  atomicAdd(&cnt[dst[e]], 1);
}

// ---------------- single-block scan -> rowptr ----------------
__global__ void k_scan(const int* __restrict__ cnt, int* __restrict__ rowptr, int N) {
  __shared__ int sums[256];
  int t = threadIdx.x;
  int chunk = (N + 255) / 256;
  int lo = t * chunk, hi = lo + chunk;
  if (hi > N) hi = N;
  if (lo > N) lo = N;
  int s = 0;
  for (int n = lo; n < hi; n++) s += cnt[n] + 1;
  sums[t] = s;
  __syncthreads();
  for (int off = 1; off < 256; off <<= 1) {
    int v = (t >= off) ? sums[t - off] : 0;
    __syncthreads();
    sums[t] += v;
    __syncthreads();
  }
  int run = sums[t] - s;  // exclusive prefix
  for (int n = lo; n < hi; n++) { rowptr[n] = run; run += cnt[n] + 1; }
  if (t == 255) rowptr[N] = run;
}

// ---------------- CSR fill (edges + self loops), also records dst per slot ----------------
__global__ void k_fill(const int* __restrict__ dst, const int* __restrict__ rowptr,
                       int* __restrict__ fill, int* __restrict__ eidx,
                       int* __restrict__ dstp, int N, int E) {
  int t = blockIdx.x * 256 + threadIdx.x;
  if (t < E) {
    int d = dst[t];
    int pos = rowptr[d] + atomicAdd(&fill[d], 1);
    eidx[pos] = t;
    dstp[pos] = d;
  } else if (t < E + N) {
    int n = t - E;
    int pos = rowptr[n + 1] - 1;
    eidx[pos] = E + n;  // self loop id
    dstp[pos] = n;
  }
}

// ---------------- loop_ea from raw ew input (flag-dispatched dtype) ----------------
__global__ __launch_bounds__(256) void k_lea(const void* __restrict__ ew,
                                             const int* __restrict__ rowptr,
                                             const int* __restrict__ eidx,
                                             float* __restrict__ lea, int N,
                                             const int* __restrict__ flag) {
  int f = flag[0];
  int wave = threadIdx.x >> 6, lane = threadIdx.x & 63;
  int node = blockIdx.x * 4 + wave;
  if (node >= N) return;
  int begin = rowptr[node], end = rowptr[node + 1] - 1;  // exclude self-loop slot
  int ch = lane & 31, half = lane >> 5;
  float s = 0.f;
  for (int p = begin + half; p < end; p += 2) {
    int eid = eidx[p];
    size_t idx = (size_t)eid * EDIMX + ch;
    s += f ? ((const float*)ew)[idx] : b2f(((const unsigned short*)ew)[idx]);
  }
  s += __shfl_xor(s, 32, 64);
  int deg = end - begin;
  if (lane < 32) lea[(size_t)node * EDIMX + ch] = s / (float)(deg > 0 ? deg : 1);
}

// ---------------- build CSR-ordered src ids + edge attrs (bf16) from raw ew ----------------
__global__ __launch_bounds__(256) void k_build_perm(const int* __restrict__ eidx,
                                                    const int* __restrict__ src,
                                                    const void* __restrict__ ew,
                                                    const float* __restrict__ lea,
                                                    int* __restrict__ srcp,
                                                    unsigned short* __restrict__ eab,
                                                    int total, int E,
                                                    const int* __restrict__ flag) {
  int f = flag[0];
  int g = blockIdx.x * 8 + (threadIdx.x >> 5);
  int lane = threadIdx.x & 31;
  if (g >= total) return;
  int eid = eidx[g];
  unsigned short v;
  int s;
  if (eid < E) {
    s = src[eid];
    size_t idx = (size_t)eid * EDIMX + lane;
    v = f ? f2b(((const float*)ew)[idx]) : ((const unsigned short*)ew)[idx];
  } else {
    s = eid - E;
    v = f2b(lea[(size_t)(eid - E) * EDIMX + lane]);
  }
  if (lane == 0) srcp[g] = s;
  eab[(size_t)g * EDIMX + lane] = v;
}

// ---------------- MFMA bf16 GEMM, NT n-tiles per block, KSTEPS known at compile time ----------
// C[M,N] = A[M,K] @ BT[N,K]^T; block covers 64 rows x NT*64 cols. K = KSTEPS*32.
template <bool BIAS, bool RELU, bool OUTBF16, int NT, int KSTEPS>
__global__ __launch_bounds__(256) void k_gemm_mfma(const unsigned short* __restrict__ A,
                                                   const unsigned short* __restrict__ BT,
                                                   const float* __restrict__ bias,
                                                   void* __restrict__ C, int M, int N) {
  const int K = KSTEPS * 32;
  int tid = threadIdx.x;
  int wave = tid >> 6, lane = tid & 63;
  int quad = lane >> 4, l16 = lane & 15;
  int m0 = blockIdx.x * 64 + (wave & 1) * 32;
  int mA0 = m0 + l16;
  if (mA0 > M - 1) mA0 = M - 1;
  int mA1 = m0 + 16 + l16;
  if (mA1 > M - 1) mA1 = M - 1;
  const bfrag* a0p = (const bfrag*)(A + (size_t)mA0 * K + quad * 8);
  const bfrag* a1p = (const bfrag*)(A + (size_t)mA1 * K + quad * 8);
#pragma unroll
  for (int j = 0; j < NT; j++) {
    int n0 = (blockIdx.y * NT + j) * 64 + (wave >> 1) * 32;
    const bfrag* b0p = (const bfrag*)(BT + (size_t)(n0 + l16) * K + quad * 8);
    const bfrag* b1p = (const bfrag*)(BT + (size_t)(n0 + 16 + l16) * K + quad * 8);
    f32x4 acc00 = {0.f, 0.f, 0.f, 0.f}, acc01 = {0.f, 0.f, 0.f, 0.f};
    f32x4 acc10 = {0.f, 0.f, 0.f, 0.f}, acc11 = {0.f, 0.f, 0.f, 0.f};
#pragma unroll 8
    for (int kk = 0; kk < KSTEPS; kk++) {
      bfrag a0 = a0p[kk * 4];
      bfrag a1 = a1p[kk * 4];
      bfrag b0 = b0p[kk * 4];
      bfrag b1 = b1p[kk * 4];
      acc00 = __builtin_amdgcn_mfma_f32_16x16x32_bf16(a0, b0, acc00, 0, 0, 0);
      acc01 = __builtin_amdgcn_mfma_f32_16x16x32_bf16(a0, b1, acc01, 0, 0, 0);
      acc10 = __builtin_amdgcn_mfma_f32_16x16x32_bf16(a1, b0, acc10, 0, 0, 0);
      acc11 = __builtin_amdgcn_mfma_f32_16x16x32_bf16(a1, b1, acc11, 0, 0, 0);
    }
    float bv0 = 0.f, bv1 = 0.f;
    if (BIAS) {
      bv0 = bias[n0 + l16];
      bv1 = bias[n0 + 16 + l16];
    }
    int col0 = n0 + l16, col1 = n0 + 16 + l16;
#pragma unroll
    for (int r = 0; r < 4; r++) {
      int row0 = m0 + quad * 4 + r;
      int row1 = m0 + 16 + quad * 4 + r;
      float v00 = acc00[r] + bv0, v01 = acc01[r] + bv1;
      float v10 = acc10[r] + bv0, v11 = acc11[r] + bv1;
      if (RELU) {
        v00 = fmaxf(v00, 0.f); v01 = fmaxf(v01, 0.f);
        v10 = fmaxf(v10, 0.f); v11 = fmaxf(v11, 0.f);
      }
      if (row0 < M) {
        if (OUTBF16) {
          ((unsigned short*)C)[(size_t)row0 * N + col0] = f2b(v00);
          ((unsigned short*)C)[(size_t)row0 * N + col1] = f2b(v01);
        } else {
          ((float*)C)[(size_t)row0 * N + col0] = v00;
          ((float*)C)[(size_t)row0 * N + col1] = v01;
        }
      }
      if (row1 < M) {
        if (OUTBF16) {
          ((unsigned short*)C)[(size_t)row1 * N + col0] = f2b(v10);
          ((unsigned short*)C)[(size_t)row1 * N + col1] = f2b(v11);
        } else {
          ((float*)C)[(size_t)row1 * N + col0] = v10;
          ((float*)C)[(size_t)row1 * N + col1] = v11;
        }
      }
    }
  }
}

// ---------------- MFMA-based edge score: 1 wave = 16 CSR slots ----------------
// xlr rows are [xl(256) | xr(256)] per node, stride 512.
__global__ __launch_bounds__(256) void k_score_mfma(
    const unsigned short* __restrict__ xlr, const unsigned short* __restrict__ eab,
    const int* __restrict__ srcp, const int* __restrict__ dstp,
    const unsigned short* __restrict__ WET, const float* __restrict__ att,
    float* __restrict__ score, int ngroups) {
  __shared__ unsigned short We_s[256 * 40];      // WET rows padded 32->40 (20.5 KB)
  __shared__ unsigned short ee_s[4][16 * 260];   // per-wave EE staging (33.3 KB)
  {
    int tid = threadIdx.x;  // one row per thread: 32 ushorts = 8x ushort4
#pragma unroll
    for (int j = 0; j < 8; j++)
      *(ushort4*)&We_s[tid * 40 + j * 4] = *(const ushort4*)(WET + tid * 32 + j * 4);
  }
  __syncthreads();
  int wave = threadIdx.x >> 6, lane = threadIdx.x & 63;
  int quad = lane >> 4, l16 = lane & 15;
  int g = blockIdx.x * 4 + wave;
  if (g >= ngroups) return;
  int pbase = g * 16;
  const bfrag ea = *(const bfrag*)(eab + ((size_t)(pbase + l16) << 5) + quad * 8);
  f32x4 zero4 = {0.f, 0.f, 0.f, 0.f};
  f32x4 acc[16];
#pragma unroll
  for (int t = 0; t < 16; t++) {
    bfrag bw = *(const bfrag*)&We_s[(t * 16 + l16) * 40 + quad * 8];
    acc[t] = __builtin_amdgcn_mfma_f32_16x16x32_bf16(ea, bw, zero4, 0, 0, 0);
  }
#pragma unroll
  for (int t = 0; t < 16; t++) {
#pragma unroll
    for (int r = 0; r < 4; r++)
      ee_s[wave][(quad * 4 + r) * 260 + t * 16 + l16] = f2b(acc[t][r]);
  }
  int c0 = lane * 4;
  float4 a4 = *(const float4*)(att + c0);
  for (int e = 0; e < 16; e += 2) {
    int p0 = pbase + e, p1 = pbase + e + 1;
    int s0 = srcp[p0], d0 = dstp[p0];
    int s1 = srcp[p1], d1 = dstp[p1];
    ushort4 vl0 = *(const ushort4*)(xlr + ((size_t)s0 << 9) + c0);
    ushort4 vr0 = *(const ushort4*)(xlr + ((size_t)d0 << 9) + 256 + c0);
    ushort4 vl1 = *(const ushort4*)(xlr + ((size_t)s1 << 9) + c0);
    ushort4 vr1 = *(const ushort4*)(xlr + ((size_t)d1 << 9) + 256 + c0);
    ushort4 eu0 = *(const ushort4*)&ee_s[wave][e * 260 + c0];
    ushort4 eu1 = *(const ushort4*)&ee_s[wave][(e + 1) * 260 + c0];
    float z00 = b2f(vl0.x) + b2f(vr0.x) + b2f(eu0.x);
    float z01 = b2f(vl0.y) + b2f(vr0.y) + b2f(eu0.y);
    float z02 = b2f(vl0.z) + b2f(vr0.z) + b2f(eu0.z);
    float z03 = b2f(vl0.w) + b2f(vr0.w) + b2f(eu0.w);
    float z10 = b2f(vl1.x) + b2f(vr1.x) + b2f(eu1.x);
    float z11 = b2f(vl1.y) + b2f(vr1.y) + b2f(eu1.y);
    float z12 = b2f(vl1.z) + b2f(vr1.z) + b2f(eu1.z);
    float z13 = b2f(vl1.w) + b2f(vr1.w) + b2f(eu1.w);
    z00 = z00 > 0.f ? z00 : 0.2f * z00; z01 = z01 > 0.f ? z01 : 0.2f * z01;
    z02 = z02 > 0.f ? z02 : 0.2f * z02; z03 = z03 > 0.f ? z03 : 0.2f * z03;
    z10 = z10 > 0.f ? z10 : 0.2f * z10; z11 = z11 > 0.f ? z11 : 0.2f * z11;
    z12 = z12 > 0.f ? z12 : 0.2f * z12; z13 = z13 > 0.f ? z13 : 0.2f * z13;
    float sc0 = z00 * a4.x + z01 * a4.y + z02 * a4.z + z03 * a4.w;
    float sc1 = z10 * a4.x + z11 * a4.y + z12 * a4.z + z13 * a4.w;
    sc0 += __shfl_xor(sc0, 1, 64);
    sc1 += __shfl_xor(sc1, 1, 64);
    sc0 += __shfl_xor(sc0, 2, 64);
    sc1 += __shfl_xor(sc1, 2, 64);
    sc0 += __shfl_xor(sc0, 4, 64);
    sc1 += __shfl_xor(sc1, 4, 64);
    if ((lane & 7) == 0) {
      int h = lane >> 3;
      score[(size_t)p0 * 8 + h] = sc0;
      score[(size_t)p1 * 8 + h] = sc1;
    }
  }
}

// ---------------- node-parallel softmax + aggregate (4-edge unrolled gathers) ----------------
__global__ __launch_bounds__(256) void k_agg(const unsigned short* __restrict__ xlr,
                                             const float* __restrict__ score,
                                             const int* __restrict__ srcp,
                                             const float* __restrict__ bias,
                                             const int* __restrict__ rowptr,
                                             float* __restrict__ out, int N) {
  int wave = threadIdx.x >> 6, lane = threadIdx.x & 63;
  int node = blockIdx.x * 4 + wave;
  if (node >= N) return;
  int begin = rowptr[node], end = rowptr[node + 1];
  int head = lane >> 3, sl = lane & 7;
  float m = -3.4e38f;
  for (int p = begin + sl; p < end; p += 8)
    m = fmaxf(m, score[(size_t)p * 8 + head]);
  m = fmaxf(m, __shfl_xor(m, 1, 64));
  m = fmaxf(m, __shfl_xor(m, 2, 64));
  m = fmaxf(m, __shfl_xor(m, 4, 64));
  float ssum = 0.f;
  for (int p = begin + sl; p < end; p += 8)
    ssum += __expf(score[(size_t)p * 8 + head] - m);
  ssum += __shfl_xor(ssum, 1, 64);
  ssum += __shfl_xor(ssum, 2, 64);
  ssum += __shfl_xor(ssum, 4, 64);
  float linv = 1.f / ssum;
  int c0 = lane * 4;
  float ax = 0.f, ay = 0.f, az = 0.f, aw = 0.f;
  for (int p = begin; p < end; p += 4) {
    int e1 = end - 1;
    int q1 = (p + 1 < end) ? p + 1 : e1;
    int q2 = (p + 2 < end) ? p + 2 : e1;
    int q3 = (p + 3 < end) ? p + 3 : e1;
    int s0 = srcp[p], s1 = srcp[q1], s2 = srcp[q2], s3 = srcp[q3];
    float sc0 = score[(size_t)p * 8 + head];
    float sc1 = score[(size_t)q1 * 8 + head];
    float sc2 = score[(size_t)q2 * 8 + head];
    float sc3 = score[(size_t)q3 * 8 + head];
    ushort4 v0 = *(const ushort4*)(xlr + ((size_t)s0 << 9) + c0);
    ushort4 v1 = *(const ushort4*)(xlr + ((size_t)s1 << 9) + c0);
    ushort4 v2 = *(const ushort4*)(xlr + ((size_t)s2 << 9) + c0);
    ushort4 v3 = *(const ushort4*)(xlr + ((size_t)s3 << 9) + c0);
    float w0 = __expf(sc0 - m) * linv;
    float w1 = (p + 1 < end) ? __expf(sc1 - m) * linv : 0.f;
    float w2 = (p + 2 < end) ? __expf(sc2 - m) * linv : 0.f;
    float w3 = (p + 3 < end) ? __expf(sc3 - m) * linv : 0.f;
    ax += w0 * b2f(v0.x) + w1 * b2f(v1.x) + w2 * b2f(v2.x) + w3 * b2f(v3.x);
    ay += w0 * b2f(v0.y) + w1 * b2f(v1.y) + w2 * b2f(v2.y) + w3 * b2f(v3.y);
    az += w0 * b2f(v0.z) + w1 * b2f(v1.z) + w2 * b2f(v2.z) + w3 * b2f(v3.z);
    aw += w0 * b2f(v0.w) + w1 * b2f(v1.w) + w2 * b2f(v2.w) + w3 * b2f(v3.w);
  }
  float4 bia = *(const float4*)(bias + c0);
  float4 acc = make_float4(ax + bia.x, ay + bia.y, az + bia.z, aw + bia.w);
  ((float4*)out)[(size_t)node * 64 + lane] = acc;
}

// ---------------- BN stats (sum, sumsq per channel) ----------------
__global__ __launch_bounds__(256) void k_bnstats(const float* __restrict__ x,
                                                 float* __restrict__ sums, int N) {
  int c = threadIdx.x;
  float s = 0.f, sq = 0.f;
  for (int n = blockIdx.x; n < N; n += gridDim.x) {
    float v = x[(size_t)n * DIMX + c];
    s += v; sq += v * v;
  }
  atomicAdd(&sums[c], s);
  atomicAdd(&sums[DIMX + c], sq);
}

// ---------------- BN + leaky_relu(0.01) + residual (+ bf16 shadow) ----------------
template <bool FINAL>
__global__ __launch_bounds__(256) void k_bnapply(const float* __restrict__ x,
                                                 const float* __restrict__ res,
                                                 const float* __restrict__ sums,
                                                 const float* __restrict__ g,
                                                 const float* __restrict__ b,
                                                 void* __restrict__ out,
                                                 unsigned short* __restrict__ outb, int N,
                                                 const int* __restrict__ flag) {
  int i = blockIdx.x * 256 + threadIdx.x;
  if (i >= N * DIMX) return;
  int c = i & (DIMX - 1);
  float invn = 1.f / (float)N;
  float mu = sums[c] * invn;
  float var = sums[DIMX + c] * invn - mu * mu;
  float rstd = rsqrtf(var + 1e-5f);
  float y = (x[i] - mu) * rstd * g[c] + b[c];
  y = y > 0.f ? y : 0.01f * y;
  y += res[i];
  if (FINAL) {
    if (flag[0]) ((float*)out)[i] = y;
    else ((unsigned short*)out)[i] = f2b(y);
  } else {
    ((float*)out)[i] = y;
    outb[i] = f2b(y);
  }
}

extern "C" void kernel_launch(void* const* d_in, const int* in_sizes, int n_in,
                              void* d_out, int out_size, void* d_ws, size_t ws_size,
                              hipStream_t stream) {
  (void)in_sizes; (void)n_in; (void)out_size; (void)ws_size;
  const int* ei = (const int*)d_in[1];
  const int* srcp = ei;
  const int* dstp = ei + NE;

  char* w = (char*)d_ws;
  auto alloc = [&](size_t bytes) {
    char* p = w;
    w += (bytes + 255) & ~(size_t)255;
    return p;
  };
  float* H0 = (float*)alloc((size_t)NN * DIMX * 4);
  float* H1 = (float*)alloc((size_t)NN * DIMX * 4);
  float* G = (float*)alloc((size_t)NN * DIMX * 4);
  float* LEA = (float*)alloc((size_t)NN * EDIMX * 4);
  float* EWF = (float*)alloc((size_t)NE * EDIMX * 4);  // only used as FF1b alias now
  float* PAR = (float*)alloc((size_t)806656 * 4);
  float* SCORE = (float*)alloc((size_t)TOT * NHEADS * 4);  // 10.9 MB
  int* CNT = (int*)alloc((size_t)NN * 4);
  int* ROWPTR = (int*)alloc((size_t)(NN + 1) * 4);
  int* FILL = (int*)alloc((size_t)NN * 4);
  int* EIDX = (int*)alloc((size_t)TOT * 4);
  int* SRCP = (int*)alloc((size_t)TOT * 4);
  int* DSTP = (int*)alloc((size_t)TOT * 4);
  float* BNS = (float*)alloc(2 * DIMX * 4);
  int* FLAG = (int*)alloc(256);
  unsigned short* H0b = (unsigned short*)alloc((size_t)NN * DIMX * 2);
  unsigned short* H1b = (unsigned short*)alloc((size_t)NN * DIMX * 2);
  unsigned short* XLRb = (unsigned short*)alloc((size_t)NN * 512 * 2);  // [xl|xr] per node
  unsigned short* EAB = (unsigned short*)alloc((size_t)TOT * EDIMX * 2);
  unsigned short* WLRT0 = (unsigned short*)alloc((size_t)512 * DIMX * 2);  // [Wl^T;Wr^T]
  unsigned short* WLRT1 = (unsigned short*)alloc((size_t)512 * DIMX * 2);
  unsigned short* WET0 = (unsigned short*)alloc((size_t)DIMX * EDIMX * 2);  // We^T [256][32]
  unsigned short* WET1 = (unsigned short*)alloc((size_t)DIMX * EDIMX * 2);
  unsigned short* W1T = (unsigned short*)alloc((size_t)DIMX * DFFX * 2);
  unsigned short* W2T = (unsigned short*)alloc((size_t)DFFX * DIMX * 2);
  unsigned short* FF1b = (unsigned short*)EWF;  // 41 MB alias, FF phase only

  // ---- dtype detect + convert params to f32 / activations to f32+bf16 ----
  k_detect<<<1, 256, 0, stream>>>((const unsigned short*)d_in[0], FLAG);
  k_cvt_dual<<<(NN * DIMX + 255) / 256, 256, 0, stream>>>(d_in[0], H0, H0b, NN * DIMX, FLAG);
  static const int psz[20] = {65536, 65536, 8192, 256, 256,
                              65536, 65536, 8192, 256, 256,
                              256, 256, 256, 256, 256, 256,
                              262144, 1024, 262144, 256};
  float* pp[20];
  {
    CvtArgs ca;
    int off = 0;
    for (int i = 0; i < 20; i++) {
      pp[i] = PAR + off;
      off += psz[i];
      ca.src[i] = d_in[3 + i];
      ca.dst[i] = pp[i];
      ca.n[i] = psz[i];
    }
    k_cvt_multi<<<dim3(262144 / 256, 20), 256, 0, stream>>>(ca, FLAG);
  }
  const float* g_att[2] = {pp[3], pp[8]};
  const float* g_b[2] = {pp[4], pp[9]};
  const float* bn_g[3] = {pp[10], pp[12], pp[14]};
  const float* bn_b[3] = {pp[11], pp[13], pp[15]};
  const float* ff_b1 = pp[17];
  const float* ff_b2 = pp[19];

  // ---- weights: bf16 [N][K] transposes; Wl/Wr stacked into one [512][256] ----
  k_transpose<<<dim3(8, 8), 256, 0, stream>>>(pp[0], WLRT0, DIMX, DIMX);
  k_transpose<<<dim3(8, 8), 256, 0, stream>>>(pp[1], WLRT0 + 256 * DIMX, DIMX, DIMX);
  k_transpose<<<dim3(8, 8), 256, 0, stream>>>(pp[5], WLRT1, DIMX, DIMX);
  k_transpose<<<dim3(8, 8), 256, 0, stream>>>(pp[6], WLRT1 + 256 * DIMX, DIMX, DIMX);
  k_transpose<<<dim3(8, 1), 256, 0, stream>>>(pp[2], WET0, EDIMX, DIMX);
  k_transpose<<<dim3(8, 1), 256, 0, stream>>>(pp[7], WET1, EDIMX, DIMX);
  k_transpose<<<dim3(32, 8), 256, 0, stream>>>(pp[16], W1T, DIMX, DFFX);
  k_transpose<<<dim3(8, 32), 256, 0, stream>>>(pp[18], W2T, DFFX, DIMX);
  const unsigned short* WLRT[2] = {WLRT0, WLRT1};
  const unsigned short* WET[2] = {WET0, WET1};

  // ---- graph structure (shared by both GAT layers) ----
  hipMemsetAsync(CNT, 0, (size_t)NN * 4, stream);
  hipMemsetAsync(FILL, 0, (size_t)NN * 4, stream);
  k_edge_count<<<(NE + 255) / 256, 256, 0, stream>>>(dstp, CNT, NE);
  k_scan<<<1, 256, 0, stream>>>(CNT, ROWPTR, NN);
  k_fill<<<(TOT + 255) / 256, 256, 0, stream>>>(dstp, ROWPTR, FILL, EIDX, DSTP, NN, NE);
  k_lea<<<(NN + 3) / 4, 256, 0, stream>>>(d_in[2], ROWPTR, EIDX, LEA, NN, FLAG);
  k_build_perm<<<(TOT + 7) / 8, 256, 0, stream>>>(EIDX, srcp, d_in[2], LEA, SRCP, EAB, TOT, NE,
                                                  FLAG);

  const int MB = (NN + 63) / 64;  // 313
  auto run_gat = [&](const float* x, const unsigned short* xb, int li, int bi, float* hout,
                     unsigned short* houtb) {
    // XL|XR in one GEMM: N=512, K=256 (KSTEPS=8), NT=2 -> grid y=4 (1252 blocks)
    k_gemm_mfma<false, false, true, 2, 8><<<dim3(MB, 4), 256, 0, stream>>>(xb, WLRT[li],
                                                                           nullptr, XLRb, NN,
                                                                           512);
    k_score_mfma<<<(NGROUPS + 3) / 4, 256, 0, stream>>>(XLRb, EAB, SRCP, DSTP, WET[li],
                                                        g_att[li], SCORE, NGROUPS);
    k_agg<<<(NN + 3) / 4, 256, 0, stream>>>(XLRb, SCORE, SRCP, g_b[li], ROWPTR, G, NN);
    hipMemsetAsync(BNS, 0, 2 * DIMX * 4, stream);
    k_bnstats<<<128, 256, 0, stream>>>(G, BNS, NN);
    k_bnapply<false><<<(NN * DIMX + 255) / 256, 256, 0, stream>>>(G, x, BNS, bn_g[bi], bn_b[bi],
                                                                  hout, houtb, NN, FLAG);
  };

  run_gat(H0, H0b, 0, 0, H1, H1b);  // h1 = nf + lrelu(bn(gat1(nf)))
  run_gat(H1, H1b, 1, 1, H0, H0b);  // h2 = h1 + lrelu(bn(gat2(h1)))

  // ---- feed-forward ----
  // FF1: N=1024, K=256 (KSTEPS=8), NT=2 -> grid y=8 (2504 blocks)
  k_gemm_mfma<true, true, true, 2, 8><<<dim3(MB, 8), 256, 0, stream>>>(H0b, W1T, ff_b1, FF1b,
                                                                       NN, DFFX);
  // FF2: N=256, K=1024 (KSTEPS=32), NT=1 -> grid y=4 (1252 blocks)
  k_gemm_mfma<true, false, false, 1, 32><<<dim3(MB, 4), 256, 0, stream>>>(FF1b, W2T, ff_b2, G,
                                                                          NN, DIMX);
  hipMemsetAsync(BNS, 0, 2 * DIMX * 4, stream);
  k_bnstats<<<128, 256, 0, stream>>>(G, BNS, NN);
  k_bnapply<true><<<(NN * DIMX + 255) / 256, 256, 0, stream>>>(G, H0, BNS, bn_g[2], bn_b[2],
                                                               d_out, nullptr, NN, FLAG);
}